// Round 15
// baseline (219.790 us; speedup 1.0000x reference)
//
#include <hip/hip_runtime.h>
#include <hip/hip_bf16.h>

// Problem constants
#define NB 512     // batch
#define NP 1152    // primary capsules
#define NC 10      // digit capsules
#define ND 16      // output capsule dim
#define NI 8       // input capsule dim

constexpr int K_B    = 2;                // b's per lane
constexpr int B_TILE = 4 * 4 * K_B;      // 32 b per block (4 waves x 4 bsub x K_B)
constexpr int P_TILE = 8;                // p's per block
constexpr int NBLK_B = NB / B_TILE;      // 16
constexpr int NBLK_P = NP / P_TILE;      // 144
constexpr int SVD = NB * NC * ND;        // 81920
constexpr int W_TILE_BYTES = P_TILE * NC * ND * NI * 4;   // 40960
constexpr int X_TILE_FLOATS = B_TILE * P_TILE * NI;       // 2048 floats = 8KB

constexpr float LOG2E = 1.4426950408889634f;

typedef float v2f __attribute__((ext_vector_type(2)));

// 16-lane all-reduce sum via DPP (quad_perm xor1, xor2; row_ror 4, 8).
// Pure VALU. Result broadcast to all 16 lanes of the row.
__device__ __forceinline__ float red16_dpp(float v) {
    int t;
    t = __builtin_amdgcn_update_dpp(0, __float_as_int(v), 0xB1, 0xF, 0xF, true); // xor1
    v += __int_as_float(t);
    t = __builtin_amdgcn_update_dpp(0, __float_as_int(v), 0x4E, 0xF, 0xF, true); // xor2
    v += __int_as_float(t);
    t = __builtin_amdgcn_update_dpp(0, __float_as_int(v), 0x124, 0xF, 0xF, true); // row_ror:4
    v += __int_as_float(t);
    t = __builtin_amdgcn_update_dpp(0, __float_as_int(v), 0x128, 0xF, 0xF, true); // row_ror:8
    v += __int_as_float(t);
    return v;
}

// squash scale factor for a d-row: s has the row's element in each lane (d=lane&15).
__device__ __forceinline__ float squash_scale(float sv) {
    const float sq = red16_dpp(sv * sv);
    return (sq / (1.0f + sq)) / sqrtf(sq + 1e-7f);
}

// One routing pass. R15 = EXACT R9 pass body (best total 180.7us; the only
// VGPR-clean single-stage structure) + INLINE SQUASH in the vr prologue.
// Occupancy avenue CLOSED by R14: occ 47% (best ever) ran SLOWER (100us) at
// VGPR=48 — pass time tracks VGPR-enabled ILP, not occupancy (80reg/26%->63us,
// 68reg/28%->73, 48reg/47%->100, spilled->95-800). Two-stage partials CLOSED:
// traffic tax cancels atomic savings (R10 182.4, R13 210 vs R9 180.7).
// R15 attacks the remaining soft cost: R9's 7-dispatch serial chain. The
// squash kernels between passes are pipeline bubbles; squash is just a
// red16 over d-rows — already available in-register in the pass prologue.
// So: pass k reads the RAW accumulator s_{k-1} (and s_{k-2} for PASS 2),
// squashes inline (once per block, ~80 VALU + 2 red16 chains per (k,c)),
// and the chain becomes memset(s0..s2) -> pass0 -> pass1 -> pass2 -> squash.
// 5 dispatches, 2 fewer bubbles, 2 fewer full-device drains.
// Grid swizzle (R9): id%16 = bblk -> per-bblk XCD affinity, x L2-local,
//   all 144 atomic contenders per address on one XCD.
// W LDS swizzle involution: S(A) = A ^ (bit7(A)<<4) ^ (bit8(A)<<5).
// x LDS swizzle (R4): physical unit u holds logical (bl, w16^(bl&3));
//   read XOR (bsub<<4) -> bsub hits bank-quads {0,4,8,12}, conflict-free.
// Softmax slimming (R2): log2(e) folded into vr, NO max-subtraction
//   (|lg*log2e| <~ 50 << 127, exp2-safe), v_rcp_f32 for 1/sum.
// VGPR-cap law (confirmed 6x): bounds(_,N) -> cap 256/N, independent of
//   block size; cap below demand = silent scratch spill.
// PASS 0: coup = 0.1;  PASS 1: logits = u.squash(s0);
// PASS 2: logits = u.(squash(s0)+squash(s1))
template<int PASS>
__global__ __launch_bounds__(256, 2)
void caps_pass(const float* __restrict__ x,    // [NB, NP, NI]
               const float* __restrict__ w,    // [NP, NC, ND, NI]
               const float* __restrict__ s0,   // raw accum from pass 0 (PASS>=1)
               const float* __restrict__ s1,   // raw accum from pass 1 (PASS==2)
               float* __restrict__ s_out)      // raw accum out [NB, NC, ND]
{
    __shared__ __align__(16) float w_lds[W_TILE_BYTES / 4];   // 40KB
    __shared__ __align__(16) float x_lds[X_TILE_FLOATS];      // 8KB, [b][pp][i] swizzled

    const int tid  = threadIdx.x;
    const int lane = tid & 63;
    const int wave = tid >> 6;           // 0..3
    const int d    = lane & 15;
    const int bsub = lane >> 4;          // 0..3
    // R9 swizzle: id = pblk*16 + bblk -> id%8 = bblk%8 -> XCD affinity.
    const int bblk = blockIdx.x % NBLK_B;
    const int pblk = blockIdx.x / NBLK_B;
    const int p0   = pblk * P_TILE;

    // ---- stage W tile: each wave loads one 10KB quarter (16B/lane, linear dest) ----
    {
        const uint8_t* wsrc = (const uint8_t*)w + (size_t)pblk * W_TILE_BYTES;
        // source offset: S(lane*16) within the 1KB chunk (bits 7,8 of chunk bases are 0)
        const int lane_src = (lane << 4) ^ ((lane & 8) << 1) ^ ((lane & 16) << 1);
        #pragma unroll
        for (int j = 0; j < 10; ++j) {
            const int off = wave * 10240 + j * 1024;
            __builtin_amdgcn_global_load_lds(
                (const __attribute__((address_space(1))) void*)(wsrc + off + lane_src),
                (__attribute__((address_space(3))) void*)((uint8_t*)w_lds + off),
                16, 0, 0);
        }
    }

    // ---- stage x tile: 8KB, linear LDS dest, swizzled global source ----
    // 16B unit u (0..511): bl = u>>4 (0..31), w16 = u&15 (= pp*2+half).
    // Physical LDS unit u holds logical unit (bl, w16 ^ (bl&3)) [byte bits 4-5].
    {
        #pragma unroll
        for (int j = 0; j < 2; ++j) {
            const int u   = wave * 128 + j * 64 + lane;
            const int bl  = u >> 4;
            const int w16 = u & 15;
            const float* bbase = x + ((size_t)(bblk * B_TILE + bl) * NP + p0) * NI;
            const uint8_t* src = (const uint8_t*)bbase + ((w16 ^ (bl & 3)) * 16);
            __builtin_amdgcn_global_load_lds(
                (const __attribute__((address_space(1))) void*)src,
                (__attribute__((address_space(3))) void*)((uint8_t*)x_lds + (size_t)u * 16),
                16, 0, 0);
        }
    }

    int bidx[K_B];
    #pragma unroll
    for (int k = 0; k < K_B; ++k) bidx[k] = bblk * B_TILE + wave * 8 + k * 4 + bsub;

    // v = squash(s0) (+ squash(s1) for PASS 2), inline, pre-scaled by log2(e).
    // Loop-invariant over p; squash = per-(b,c) d-row red16, layout matches
    // lanes exactly (d = lane&15). Runs once per block, hides under staging.
    float vr[K_B][NC];
    if (PASS >= 1) {
        #pragma unroll
        for (int k = 0; k < K_B; ++k)
            #pragma unroll
            for (int c = 0; c < NC; ++c) {
                const int gi = (bidx[k] * NC + c) * ND + d;
                const float a0 = s0[gi];
                float vv = a0 * squash_scale(a0);
                if (PASS == 2) {
                    const float a1 = s1[gi];
                    vv += a1 * squash_scale(a1);
                }
                vr[k][c] = vv * LOG2E;
            }
    }

    float sacc[K_B][NC];
    #pragma unroll
    for (int k = 0; k < K_B; ++k)
        #pragma unroll
        for (int c = 0; c < NC; ++c) sacc[k][c] = 0.0f;

    // swizzled read offset for W[pp,c,d,0:4]: A = d*32 -> A ^ (bit2(d)<<4) ^ (bit3(d)<<5).
    // Half 2 at A+16 = lane_rd^16 (bit4 flip, bits 7,8 unchanged).
    const int lane_rd = (d << 5) ^ ((d & 4) << 2) ^ ((d & 8) << 2);
    const int xswz    = bsub << 4;   // x read swizzle (byte bits 4-5 ^= b&3)

    asm volatile("s_waitcnt vmcnt(0)" ::: "memory");   // W + x staging complete
    __syncthreads();                                   // all quarters visible to all waves

    for (int pp = 0; pp < P_TILE; ++pp) {
        v2f xv[K_B][4];
        #pragma unroll
        for (int k = 0; k < K_B; ++k) {
            const int xb = ((wave * 8 + k * 4 + bsub) * 256 + pp * 32) ^ xswz;
            const uint8_t* xp = (const uint8_t*)x_lds;
            const float4 a = *(const float4*)(xp + xb);
            const float4 b = *(const float4*)(xp + (xb ^ 16));
            xv[k][0] = v2f{a.x, a.y};
            xv[k][1] = v2f{a.z, a.w};
            xv[k][2] = v2f{b.x, b.y};
            xv[k][3] = v2f{b.z, b.w};
        }

        float uh[K_B][NC];
        #pragma unroll
        for (int c = 0; c < NC; ++c) {
            const uint8_t* pb = (const uint8_t*)w_lds + pp * 5120 + c * 512;
            const float4 wa = *(const float4*)(pb + lane_rd);          // W[p,c,d,0:4]
            const float4 wb = *(const float4*)(pb + (lane_rd ^ 16));   // W[p,c,d,4:8]
            const v2f w01{wa.x, wa.y}, w23{wa.z, wa.w};
            const v2f w45{wb.x, wb.y}, w67{wb.z, wb.w};
            #pragma unroll
            for (int k = 0; k < K_B; ++k) {
                v2f acc = w01 * xv[k][0];                              // v_pk_mul_f32
                acc = __builtin_elementwise_fma(w23, xv[k][1], acc);   // v_pk_fma_f32
                acc = __builtin_elementwise_fma(w45, xv[k][2], acc);
                acc = __builtin_elementwise_fma(w67, xv[k][3], acc);
                const float u = acc[0] + acc[1];
                if (PASS == 0) sacc[k][c] = fmaf(0.1f, u, sacc[k][c]);
                else           uh[k][c] = u;
            }
        }

        if (PASS >= 1) {
            #pragma unroll
            for (int k = 0; k < K_B; ++k) {
                float lg[NC];
                #pragma unroll
                for (int c = 0; c < NC; ++c)
                    lg[c] = red16_dpp(uh[k][c] * vr[k][c]);   // log2-domain logits
                float ssum = 0.0f;
                float coup[NC];
                #pragma unroll
                for (int c = 0; c < NC; ++c) {
                    coup[c] = __builtin_amdgcn_exp2f(lg[c]);  // no max-sub: bounded
                    ssum += coup[c];
                }
                const float inv = __builtin_amdgcn_rcpf(ssum);
                #pragma unroll
                for (int c = 0; c < NC; ++c)
                    sacc[k][c] = fmaf(coup[c] * inv, uh[k][c], sacc[k][c]);
            }
        }
    }

    // tail: each thread owns distinct (b,d) -> 10 atomics per k, no redundancy.
    // R9 swizzle keeps all 144 contenders per address on one XCD.
    #pragma unroll
    for (int k = 0; k < K_B; ++k)
        #pragma unroll
        for (int c = 0; c < NC; ++c)
            atomicAdd(&s_out[(bidx[k] * NC + c) * ND + d], sacc[k][c]);
}

// Final squash: v = (|s|^2/(1+|s|^2)) * s / sqrt(|s|^2+1e-7), d-rows = 16 lanes.
__global__ __launch_bounds__(256)
void caps_squash(const float* __restrict__ s, float* __restrict__ v)
{
    const int idx = blockIdx.x * 256 + threadIdx.x;
    const float sv = s[idx];
    v[idx] = sv * squash_scale(sv);
}

extern "C" void kernel_launch(void* const* d_in, const int* in_sizes, int n_in,
                              void* d_out, int out_size, void* d_ws, size_t ws_size,
                              hipStream_t stream)
{
    const float* x = (const float*)d_in[0];
    const float* w = (const float*)d_in[1];
    float* out = (float*)d_out;

    float* s0 = (float*)d_ws;        // raw accum, pass 0
    float* s1 = s0 + SVD;            // raw accum, pass 1
    float* s2 = s1 + SVD;            // raw accum, pass 2

    const dim3 pgrid(NBLK_B * NBLK_P);   // 2304 blocks of 256
    const dim3 pblock(256);
    const dim3 qgrid(SVD / 256);         // 320
    const dim3 qblock(256);

    // one memset zeroes all three accumulators (960KB)
    hipMemsetAsync(s0, 0, (size_t)3 * SVD * sizeof(float), stream);
    caps_pass<0><<<pgrid, pblock, 0, stream>>>(x, w, nullptr, nullptr, s0);
    caps_pass<1><<<pgrid, pblock, 0, stream>>>(x, w, s0, nullptr, s1);
    caps_pass<2><<<pgrid, pblock, 0, stream>>>(x, w, s0, s1, s2);
    caps_squash<<<qgrid, qblock, 0, stream>>>(s2, out);
}

// Round 16
// 180.877 us; speedup vs baseline: 1.2151x; 1.2151x over previous
//
#include <hip/hip_runtime.h>
#include <hip/hip_bf16.h>

// Problem constants
#define NB 512     // batch
#define NP 1152    // primary capsules
#define NC 10      // digit capsules
#define ND 16      // output capsule dim
#define NI 8       // input capsule dim

constexpr int K_B    = 2;                // b's per lane
constexpr int B_TILE = 4 * 4 * K_B;      // 32 b per block (4 waves x 4 bsub x K_B)
constexpr int P_TILE = 8;                // p's per block
constexpr int NBLK_B = NB / B_TILE;      // 16
constexpr int NBLK_P = NP / P_TILE;      // 144
constexpr int SVD = NB * NC * ND;        // 81920
constexpr int W_TILE_BYTES = P_TILE * NC * ND * NI * 4;   // 40960
constexpr int X_TILE_FLOATS = B_TILE * P_TILE * NI;       // 2048 floats = 8KB

constexpr float LOG2E = 1.4426950408889634f;

typedef float v2f __attribute__((ext_vector_type(2)));

// 16-lane all-reduce sum via DPP (quad_perm xor1, xor2; row_ror 4, 8).
// Pure VALU. Result broadcast to all 16 lanes of the row.
__device__ __forceinline__ float red16_dpp(float v) {
    int t;
    t = __builtin_amdgcn_update_dpp(0, __float_as_int(v), 0xB1, 0xF, 0xF, true); // xor1
    v += __int_as_float(t);
    t = __builtin_amdgcn_update_dpp(0, __float_as_int(v), 0x4E, 0xF, 0xF, true); // xor2
    v += __int_as_float(t);
    t = __builtin_amdgcn_update_dpp(0, __float_as_int(v), 0x124, 0xF, 0xF, true); // row_ror:4
    v += __int_as_float(t);
    t = __builtin_amdgcn_update_dpp(0, __float_as_int(v), 0x128, 0xF, 0xF, true); // row_ror:8
    v += __int_as_float(t);
    return v;
}

// One routing pass. FINAL = R9 (measured best: 180.7us total).
// Session conclusions (15 rounds of counter evidence):
//  - Kept: softmax slimming (log2e folded into vr, no max-sub, v_rcp),
//    x staged in LDS (removed per-iteration HBM latency), x XOR-swizzle
//    (bank-conflict-free), XCD atomic-affinity grid swizzle (bblk = id%16:
//    all 144 contenders per output address on one XCD, +10us).
//  - Closed: occupancy (pass time tracks VGPR-enabled ILP, not waves/CU:
//    80reg/26%occ->63us vs 48reg/47%occ->100us); two-stage partials
//    (traffic tax >= atomic savings); multi-tile accumulation (register
//    blow-up -> scratch, 2x confirmed); inline-squash fusion (prologue
//    serialization, +35us/pass).
//  - Residual LDS bank conflicts (5.9M, constant) are the W-read
//    2-per-bank-quad pigeonhole floor: 2-way aliasing is free on CDNA4.
//  - Pass decomposition: ~35us LDS-pipe floor + ~20us VALU + ~10us atomics.
// VGPR-cap law (confirmed 6x): __launch_bounds__(_,N) -> compiler VGPR cap
// = 256/N, independent of block size; cap below demand = silent scratch
// spill (signature: FETCH/WRITE inflation, VALUBusy collapse).
// Lane = (bsub 2b | d 4b); wave w handles b = w*8 + k*4 + bsub.
// W LDS swizzle involution: S(A) = A ^ (bit7(A)<<4) ^ (bit8(A)<<5).
// x LDS swizzle: physical unit u holds logical (bl, w16^(bl&3));
//   read XOR (bsub<<4) -> bsub hits bank-quads {0,4,8,12}, conflict-free.
// PASS 0: coup = 0.1;  PASS 1: logits = u.v0;  PASS 2: logits = u.(v0+v1)
template<int PASS>
__global__ __launch_bounds__(256, 2)
void caps_pass(const float* __restrict__ x,    // [NB, NP, NI]
               const float* __restrict__ w,    // [NP, NC, ND, NI]
               const float* __restrict__ v0,   // [NB, NC, ND]
               const float* __restrict__ v1,   // [NB, NC, ND]
               float* __restrict__ s_out)      // [NB, NC, ND]
{
    __shared__ __align__(16) float w_lds[W_TILE_BYTES / 4];   // 40KB
    __shared__ __align__(16) float x_lds[X_TILE_FLOATS];      // 8KB, [b][pp][i] swizzled

    const int tid  = threadIdx.x;
    const int lane = tid & 63;
    const int wave = tid >> 6;           // 0..3
    const int d    = lane & 15;
    const int bsub = lane >> 4;          // 0..3
    // XCD swizzle: id = pblk*16 + bblk -> id%8 = bblk%8 -> per-bblk affinity.
    const int bblk = blockIdx.x % NBLK_B;
    const int pblk = blockIdx.x / NBLK_B;
    const int p0   = pblk * P_TILE;

    // ---- stage W tile: each wave loads one 10KB quarter (16B/lane, linear dest) ----
    {
        const uint8_t* wsrc = (const uint8_t*)w + (size_t)pblk * W_TILE_BYTES;
        // source offset: S(lane*16) within the 1KB chunk (bits 7,8 of chunk bases are 0)
        const int lane_src = (lane << 4) ^ ((lane & 8) << 1) ^ ((lane & 16) << 1);
        #pragma unroll
        for (int j = 0; j < 10; ++j) {
            const int off = wave * 10240 + j * 1024;
            __builtin_amdgcn_global_load_lds(
                (const __attribute__((address_space(1))) void*)(wsrc + off + lane_src),
                (__attribute__((address_space(3))) void*)((uint8_t*)w_lds + off),
                16, 0, 0);
        }
    }

    // ---- stage x tile: 8KB, linear LDS dest, swizzled global source ----
    // 16B unit u (0..511): bl = u>>4 (0..31), w16 = u&15 (= pp*2+half).
    // Physical LDS unit u holds logical unit (bl, w16 ^ (bl&3)) [byte bits 4-5].
    // Source strips stay 256B-contiguous per b.
    {
        #pragma unroll
        for (int j = 0; j < 2; ++j) {
            const int u   = wave * 128 + j * 64 + lane;
            const int bl  = u >> 4;
            const int w16 = u & 15;
            const float* bbase = x + ((size_t)(bblk * B_TILE + bl) * NP + p0) * NI;
            const uint8_t* src = (const uint8_t*)bbase + ((w16 ^ (bl & 3)) * 16);
            __builtin_amdgcn_global_load_lds(
                (const __attribute__((address_space(1))) void*)src,
                (__attribute__((address_space(3))) void*)((uint8_t*)x_lds + (size_t)u * 16),
                16, 0, 0);
        }
    }

    int bidx[K_B];
    #pragma unroll
    for (int k = 0; k < K_B; ++k) bidx[k] = bblk * B_TILE + wave * 8 + k * 4 + bsub;

    // v (v0, or v0+v1 for pass 2), pre-scaled by log2(e) — loop-invariant over p
    float vr[K_B][NC];
    if (PASS >= 1) {
        #pragma unroll
        for (int k = 0; k < K_B; ++k)
            #pragma unroll
            for (int c = 0; c < NC; ++c) {
                float vv = v0[(bidx[k] * NC + c) * ND + d];
                if (PASS == 2) vv += v1[(bidx[k] * NC + c) * ND + d];
                vr[k][c] = vv * LOG2E;
            }
    }

    float sacc[K_B][NC];
    #pragma unroll
    for (int k = 0; k < K_B; ++k)
        #pragma unroll
        for (int c = 0; c < NC; ++c) sacc[k][c] = 0.0f;

    // swizzled read offset for W[pp,c,d,0:4]: A = d*32 -> A ^ (bit2(d)<<4) ^ (bit3(d)<<5).
    // Half 2 at A+16 = lane_rd^16 (bit4 flip, bits 7,8 unchanged).
    const int lane_rd = (d << 5) ^ ((d & 4) << 2) ^ ((d & 8) << 2);
    const int xswz    = bsub << 4;   // x read swizzle (byte bits 4-5 ^= b&3)

    asm volatile("s_waitcnt vmcnt(0)" ::: "memory");   // W + x staging complete
    __syncthreads();                                   // all quarters visible to all waves

    for (int pp = 0; pp < P_TILE; ++pp) {
        v2f xv[K_B][4];
        #pragma unroll
        for (int k = 0; k < K_B; ++k) {
            const int xb = ((wave * 8 + k * 4 + bsub) * 256 + pp * 32) ^ xswz;
            const uint8_t* xp = (const uint8_t*)x_lds;
            const float4 a = *(const float4*)(xp + xb);
            const float4 b = *(const float4*)(xp + (xb ^ 16));
            xv[k][0] = v2f{a.x, a.y};
            xv[k][1] = v2f{a.z, a.w};
            xv[k][2] = v2f{b.x, b.y};
            xv[k][3] = v2f{b.z, b.w};
        }

        float uh[K_B][NC];
        #pragma unroll
        for (int c = 0; c < NC; ++c) {
            const uint8_t* pb = (const uint8_t*)w_lds + pp * 5120 + c * 512;
            const float4 wa = *(const float4*)(pb + lane_rd);          // W[p,c,d,0:4]
            const float4 wb = *(const float4*)(pb + (lane_rd ^ 16));   // W[p,c,d,4:8]
            const v2f w01{wa.x, wa.y}, w23{wa.z, wa.w};
            const v2f w45{wb.x, wb.y}, w67{wb.z, wb.w};
            #pragma unroll
            for (int k = 0; k < K_B; ++k) {
                v2f acc = w01 * xv[k][0];                              // v_pk_mul_f32
                acc = __builtin_elementwise_fma(w23, xv[k][1], acc);   // v_pk_fma_f32
                acc = __builtin_elementwise_fma(w45, xv[k][2], acc);
                acc = __builtin_elementwise_fma(w67, xv[k][3], acc);
                const float u = acc[0] + acc[1];
                if (PASS == 0) sacc[k][c] = fmaf(0.1f, u, sacc[k][c]);
                else           uh[k][c] = u;
            }
        }

        if (PASS >= 1) {
            #pragma unroll
            for (int k = 0; k < K_B; ++k) {
                float lg[NC];
                #pragma unroll
                for (int c = 0; c < NC; ++c)
                    lg[c] = red16_dpp(uh[k][c] * vr[k][c]);   // log2-domain logits
                float ssum = 0.0f;
                float coup[NC];
                #pragma unroll
                for (int c = 0; c < NC; ++c) {
                    coup[c] = __builtin_amdgcn_exp2f(lg[c]);  // no max-sub: bounded
                    ssum += coup[c];
                }
                const float inv = __builtin_amdgcn_rcpf(ssum);
                #pragma unroll
                for (int c = 0; c < NC; ++c)
                    sacc[k][c] = fmaf(coup[c] * inv, uh[k][c], sacc[k][c]);
            }
        }
    }

    // tail: each thread owns distinct (b,d) -> 10 atomics per k, no redundancy.
    // XCD swizzle keeps all 144 contenders per address on one XCD.
    #pragma unroll
    for (int k = 0; k < K_B; ++k)
        #pragma unroll
        for (int c = 0; c < NC; ++c)
            atomicAdd(&s_out[(bidx[k] * NC + c) * ND + d], sacc[k][c]);
}

// v = (|s|^2/(1+|s|^2)) * s / sqrt(|s|^2+1e-7), norm over d (16-lane rows).
// ZERO_S: re-zero s for the next routing pass (replaces a hipMemsetAsync).
template<bool ZERO_S>
__global__ __launch_bounds__(256)
void caps_squash(float* __restrict__ s, float* __restrict__ v)
{
    const int idx = blockIdx.x * 256 + threadIdx.x;
    const float sv = s[idx];
    if (ZERO_S) s[idx] = 0.0f;
    float sq = red16_dpp(sv * sv);
    const float scale = (sq / (1.0f + sq)) / sqrtf(sq + 1e-7f);
    v[idx] = scale * sv;
}

extern "C" void kernel_launch(void* const* d_in, const int* in_sizes, int n_in,
                              void* d_out, int out_size, void* d_ws, size_t ws_size,
                              hipStream_t stream)
{
    const float* x = (const float*)d_in[0];
    const float* w = (const float*)d_in[1];
    float* out = (float*)d_out;

    float* s  = (float*)d_ws;       // [NB,NC,ND]
    float* v0 = s + SVD;            // [NB,NC,ND]
    float* v1 = out;                // reuse output buffer (overwritten by final squash)

    const dim3 pgrid(NBLK_B * NBLK_P);   // 2304 blocks of 256
    const dim3 pblock(256);
    const dim3 qgrid(SVD / 256);         // 320
    const dim3 qblock(256);

    hipMemsetAsync(s, 0, (size_t)SVD * sizeof(float), stream);
    caps_pass<0><<<pgrid, pblock, 0, stream>>>(x, w, nullptr, nullptr, s);
    caps_squash<true><<<qgrid, qblock, 0, stream>>>(s, v0);
    caps_pass<1><<<pgrid, pblock, 0, stream>>>(x, w, v0, nullptr, s);
    caps_squash<true><<<qgrid, qblock, 0, stream>>>(s, v1);
    caps_pass<2><<<pgrid, pblock, 0, stream>>>(x, w, v0, v1, s);
    caps_squash<false><<<qgrid, qblock, 0, stream>>>(s, out);
}